// Round 4
// baseline (21.366 us; speedup 1.0000x reference)
//
#include <hip/hip_runtime.h>

// A (256, 512, 2) f32, B (2, 1024) f32, out (256, 1) f32.
constexpr int BATCH  = 256;
constexpr int MAXLEN = 512;
constexpr int LENF   = 1024;

// out[b] = bump( max_c min_{l,j} q(l, c + j*512) ),  c in [0,512), j in {0,1}
//   q(l,f) = max(|A[b,l,0]-B[0,f]|, |A[b,l,1]-B[1,f]|)
//   bump(t) = e/(1+e)^2, e = exp(-10 t)
// (math verified absmax==0 in R1..R3)
//
// One block per batch, 1024 threads = 16 waves/CU (vs 8 in R3): thread
// (c, h) owns c-pair c for l-half h (min over l commutes with the split).
// A reads are wave-uniform -> s_load into SGPRs; inner loop is pure VALU,
// 7 ops per (l,c) covering both paired f columns.
__global__ __launch_bounds__(1024)
void chebbump_kernel(const float* __restrict__ A,
                     const float* __restrict__ B,
                     float* __restrict__ out)
{
    const int b = blockIdx.x;
    const int t = threadIdx.x;
    const int c = t & (MAXLEN - 1);   // c in [0, 512)
    const int h = t >> 9;             // l-half: 0 -> [0,256), 1 -> [256,512)

    // This half's A slice (uniform per wave -> scalar loads).
    const float* __restrict__ Ab = A + (size_t)b * (MAXLEN * 2) + h * MAXLEN;

    // This thread's two B columns (f = c and f = c + 512).
    const float b0c = B[c];
    const float b1c = B[LENF + c];
    const float b0d = B[c + MAXLEN];
    const float b1d = B[LENF + MAXLEN + c];

    // 4 independent min chains over this half's 256 l values.
    float u0 = 3.4e38f, u1 = 3.4e38f, u2 = 3.4e38f, u3 = 3.4e38f;
#pragma unroll 4
    for (int l = 0; l < MAXLEN / 2; l += 4) {
        const float a00 = Ab[2 * l + 0], a10 = Ab[2 * l + 1];
        const float a01 = Ab[2 * l + 2], a11 = Ab[2 * l + 3];
        const float a02 = Ab[2 * l + 4], a12 = Ab[2 * l + 5];
        const float a03 = Ab[2 * l + 6], a13 = Ab[2 * l + 7];
        u0 = fminf(u0, fminf(fmaxf(fabsf(a00 - b0c), fabsf(a10 - b1c)),
                             fmaxf(fabsf(a00 - b0d), fabsf(a10 - b1d))));
        u1 = fminf(u1, fminf(fmaxf(fabsf(a01 - b0c), fabsf(a11 - b1c)),
                             fmaxf(fabsf(a01 - b0d), fabsf(a11 - b1d))));
        u2 = fminf(u2, fminf(fmaxf(fabsf(a02 - b0c), fabsf(a12 - b1c)),
                             fmaxf(fabsf(a02 - b0d), fabsf(a12 - b1d))));
        u3 = fminf(u3, fminf(fmaxf(fabsf(a03 - b0c), fabsf(a13 - b1c)),
                             fmaxf(fabsf(a03 - b0d), fabsf(a13 - b1d))));
    }
    float v = fminf(fminf(u0, u1), fminf(u2, u3));

    // Combine the two l-halves of each c (min), then block-wide max over c.
    __shared__ float su[1024];
    __shared__ float sw[8];
    su[t] = v;
    __syncthreads();
    if (t < MAXLEN) {
        v = fminf(su[t], su[t + MAXLEN]);   // join l-halves
#pragma unroll
        for (int off = 32; off > 0; off >>= 1)
            v = fmaxf(v, __shfl_xor(v, off));   // 64-lane wave max
        if ((t & 63) == 0) sw[t >> 6] = v;
    }
    __syncthreads();

    if (t == 0) {
        float m = sw[0];
#pragma unroll
        for (int i = 1; i < 8; ++i) m = fmaxf(m, sw[i]);
        const float e = expf(-10.0f * m);   // m >= 0, e <= 1: stable
        const float d = 1.0f + e;
        out[b] = e / (d * d);               // sigmoid(10t)*sigmoid(-10t)
    }
}

extern "C" void kernel_launch(void* const* d_in, const int* in_sizes, int n_in,
                              void* d_out, int out_size, void* d_ws, size_t ws_size,
                              hipStream_t stream)
{
    const float* A = (const float*)d_in[0];
    const float* B = (const float*)d_in[1];
    float* out = (float*)d_out;

    hipLaunchKernelGGL(chebbump_kernel, dim3(BATCH), dim3(1024), 0, stream,
                       A, B, out);
}

// Round 5
// 18.371 us; speedup vs baseline: 1.1631x; 1.1631x over previous
//
#include <hip/hip_runtime.h>

// A (256, 512, 2) f32, B (2, 1024) f32, out (256, 1) f32.
constexpr int BATCH  = 256;
constexpr int MAXLEN = 512;
constexpr int LENF   = 1024;
constexpr int NQ     = 4;             // l-range split into 4 block-level quarters
constexpr int LQ     = MAXLEN / NQ;   // 128 l per block

// out[b] = bump( max_c min_{l,j} q(l, c + j*512) ),  c in [0,512), j in {0,1}
//   q(l,f) = max(|A[b,l,0]-B[0,f]|, |A[b,l,1]-B[1,f]|)
//   bump(t) = e/(1+e)^2, e = exp(-10 t)
// (math verified absmax==0 in R1..R4)
//
// Kernel 1: 1024 blocks = (batch, l-quarter) x 512 threads (one c-pair each).
// The A slice pointer depends on blockIdx ONLY -> provably uniform -> s_load
// into SGPRs (R4 lesson: threadIdx-derived slicing kills this). Inner loop is
// pure VALU, 7 ops per (l, c-pair). 4 blocks/CU x 8 waves = 32 waves/CU.
// Each thread writes its partial min straight to ws — no LDS, no reduction.
__global__ __launch_bounds__(512)
void chebmin_part_kernel(const float* __restrict__ A,
                         const float* __restrict__ B,
                         float* __restrict__ part)
{
    const int bid = blockIdx.x;
    const int b   = bid >> 2;          // batch
    const int q   = bid & 3;           // l-quarter
    const int c   = threadIdx.x;       // c in [0, 512)

    // Uniform (blockIdx-only) A slice: 128 l pairs = 1 KB -> scalar loads.
    const float* __restrict__ Ab = A + (size_t)b * (MAXLEN * 2) + q * (LQ * 2);

    // This thread's two B columns (f = c and f = c + 512), coalesced.
    const float b0c = B[c];
    const float b1c = B[LENF + c];
    const float b0d = B[MAXLEN + c];
    const float b1d = B[LENF + MAXLEN + c];

    // 4 independent min chains over this quarter's 128 l values.
    float u0 = 3.4e38f, u1 = 3.4e38f, u2 = 3.4e38f, u3 = 3.4e38f;
#pragma unroll 4
    for (int l = 0; l < LQ; l += 4) {
        const float a00 = Ab[2 * l + 0], a10 = Ab[2 * l + 1];
        const float a01 = Ab[2 * l + 2], a11 = Ab[2 * l + 3];
        const float a02 = Ab[2 * l + 4], a12 = Ab[2 * l + 5];
        const float a03 = Ab[2 * l + 6], a13 = Ab[2 * l + 7];
        u0 = fminf(u0, fminf(fmaxf(fabsf(a00 - b0c), fabsf(a10 - b1c)),
                             fmaxf(fabsf(a00 - b0d), fabsf(a10 - b1d))));
        u1 = fminf(u1, fminf(fmaxf(fabsf(a01 - b0c), fabsf(a11 - b1c)),
                             fmaxf(fabsf(a01 - b0d), fabsf(a11 - b1d))));
        u2 = fminf(u2, fminf(fmaxf(fabsf(a02 - b0c), fabsf(a12 - b1c)),
                             fmaxf(fabsf(a02 - b0d), fabsf(a12 - b1d))));
        u3 = fminf(u3, fminf(fmaxf(fabsf(a03 - b0c), fabsf(a13 - b1c)),
                             fmaxf(fabsf(a03 - b0d), fabsf(a13 - b1d))));
    }

    // Partial min for this (batch, quarter, c): one coalesced store, no LDS.
    part[(size_t)bid * MAXLEN + c] = fminf(fminf(u0, u1), fminf(u2, u3));
}

// Kernel 2: join the 4 l-quarters (min), block max-reduce over c, apply bump.
__global__ __launch_bounds__(512)
void combine_bump_kernel(const float* __restrict__ part,
                         float* __restrict__ out)
{
    const int b = blockIdx.x;
    const int c = threadIdx.x;
    const float* __restrict__ p = part + (size_t)b * (NQ * MAXLEN);

    float v = fminf(fminf(p[c], p[MAXLEN + c]),
                    fminf(p[2 * MAXLEN + c], p[3 * MAXLEN + c]));

    __shared__ float sw[8];
#pragma unroll
    for (int off = 32; off > 0; off >>= 1)
        v = fmaxf(v, __shfl_xor(v, off));   // 64-lane wave max
    if ((c & 63) == 0) sw[c >> 6] = v;
    __syncthreads();

    if (c == 0) {
        float m = sw[0];
#pragma unroll
        for (int i = 1; i < 8; ++i) m = fmaxf(m, sw[i]);
        const float e = expf(-10.0f * m);   // m >= 0, e <= 1: stable
        const float d = 1.0f + e;
        out[b] = e / (d * d);               // sigmoid(10t)*sigmoid(-10t)
    }
}

extern "C" void kernel_launch(void* const* d_in, const int* in_sizes, int n_in,
                              void* d_out, int out_size, void* d_ws, size_t ws_size,
                              hipStream_t stream)
{
    const float* A = (const float*)d_in[0];
    const float* B = (const float*)d_in[1];
    float* out  = (float*)d_out;
    float* part = (float*)d_ws;   // 1024 blocks x 512 floats = 2 MB scratch,
                                  // fully rewritten every call (deterministic).

    hipLaunchKernelGGL(chebmin_part_kernel, dim3(BATCH * NQ), dim3(512), 0, stream,
                       A, B, part);
    hipLaunchKernelGGL(combine_bump_kernel, dim3(BATCH), dim3(512), 0, stream,
                       part, out);
}

// Round 6
// 18.230 us; speedup vs baseline: 1.1720x; 1.0077x over previous
//
#include <hip/hip_runtime.h>

// A (256, 512, 2) f32, B (2, 1024) f32, out (256, 1) f32.
constexpr int BATCH  = 256;
constexpr int MAXLEN = 512;
constexpr int LENF   = 1024;

typedef float f2 __attribute__((ext_vector_type(2)));

// out[b] = bump( max_c min_{l,j} q(l, c + j*512) ),  c in [0,512), j in {0,1}
//   q(l,f) = max(|A[b,l,0]-B[0,f]|, |A[b,l,1]-B[1,f]|)
//   bump(t) = e/(1+e)^2, e = exp(-10 t)
// (math verified absmax==0 in R1..R5)
//
// Single dispatch: 256 blocks (1/batch) x 1024 threads = 16 waves/CU.
// Thread (c, h): c-pair c, l-half h. h is wave-constant (waves 0-7: h=0,
// 8-15: h=1) but LLVM can't prove it -> readfirstlane forces it into an
// SGPR so the A slice pointer stays uniform -> s_load (R4 lesson).
// Inner body uses float2 ext-vector subs -> v_pk_add_f32: 5 VALU ops per
// (l, c-pair) covering both paired f columns.
__global__ __launch_bounds__(1024)
void chebbump_kernel(const float* __restrict__ A,
                     const float* __restrict__ B,
                     float* __restrict__ out)
{
    const int b = blockIdx.x;
    const int t = threadIdx.x;
    const int c = t & (MAXLEN - 1);                        // c in [0, 512)
    const int h = __builtin_amdgcn_readfirstlane(t >> 9);  // l-half, SGPR

    // Uniform A slice for this half: 256 (a0,a1) pairs -> scalar loads.
    const f2* __restrict__ A2 =
        reinterpret_cast<const f2*>(A + (size_t)b * (MAXLEN * 2)) + h * (MAXLEN / 2);

    // This thread's two B columns (f = c and f = c + 512), coalesced.
    const f2 bc = { B[c],          B[LENF + c] };
    const f2 bd = { B[MAXLEN + c], B[LENF + MAXLEN + c] };

    // 4 independent min chains over this half's 256 l values.
    float u0 = 3.4e38f, u1 = 3.4e38f, u2 = 3.4e38f, u3 = 3.4e38f;
#pragma unroll 4
    for (int l = 0; l < MAXLEN / 2; l += 4) {
        const f2 a0 = A2[l + 0];
        const f2 a1 = A2[l + 1];
        const f2 a2 = A2[l + 2];
        const f2 a3 = A2[l + 3];
        const f2 d0c = a0 - bc, d0d = a0 - bd;   // v_pk_add_f32 (neg mod)
        const f2 d1c = a1 - bc, d1d = a1 - bd;
        const f2 d2c = a2 - bc, d2d = a2 - bd;
        const f2 d3c = a3 - bc, d3d = a3 - bd;
        u0 = fminf(u0, fminf(fmaxf(fabsf(d0c.x), fabsf(d0c.y)),
                             fmaxf(fabsf(d0d.x), fabsf(d0d.y))));
        u1 = fminf(u1, fminf(fmaxf(fabsf(d1c.x), fabsf(d1c.y)),
                             fmaxf(fabsf(d1d.x), fabsf(d1d.y))));
        u2 = fminf(u2, fminf(fmaxf(fabsf(d2c.x), fabsf(d2c.y)),
                             fmaxf(fabsf(d2d.x), fabsf(d2d.y))));
        u3 = fminf(u3, fminf(fmaxf(fabsf(d3c.x), fabsf(d3c.y)),
                             fmaxf(fabsf(d3d.x), fabsf(d3d.y))));
    }
    float v = fminf(fminf(u0, u1), fminf(u2, u3));

    // Join the two l-halves of each c (min), then block-wide max over c.
    __shared__ float su[1024];
    __shared__ float sw[8];
    su[t] = v;
    __syncthreads();
    if (t < MAXLEN) {
        v = fminf(su[t], su[t + MAXLEN]);   // join l-halves
#pragma unroll
        for (int off = 32; off > 0; off >>= 1)
            v = fmaxf(v, __shfl_xor(v, off));   // 64-lane wave max
        if ((t & 63) == 0) sw[t >> 6] = v;
    }
    __syncthreads();

    if (t == 0) {
        float m = sw[0];
#pragma unroll
        for (int i = 1; i < 8; ++i) m = fmaxf(m, sw[i]);
        const float e = expf(-10.0f * m);   // m >= 0, e <= 1: stable
        const float d = 1.0f + e;
        out[b] = e / (d * d);               // sigmoid(10t)*sigmoid(-10t)
    }
}

extern "C" void kernel_launch(void* const* d_in, const int* in_sizes, int n_in,
                              void* d_out, int out_size, void* d_ws, size_t ws_size,
                              hipStream_t stream)
{
    const float* A = (const float*)d_in[0];
    const float* B = (const float*)d_in[1];
    float* out = (float*)d_out;

    hipLaunchKernelGGL(chebbump_kernel, dim3(BATCH), dim3(1024), 0, stream,
                       A, B, out);
}